// Round 9
// baseline (8438.603 us; speedup 1.0000x reference)
//
#include <hip/hip_runtime.h>

// LSTM T=16384, B=32, H=96. One block per batch (32 blocks x 192 threads).
// R8 analysis: halving issue work only cut step time 1430->1200 cyc => a
// ~900cyc fixed cost (barrier across 6 waves + LDS round trip + serial tail)
// dominates. This round: 2 threads/cell (3 waves only). Thread (j=tid>>1,
// sh=tid&1) holds ALL 4 gate rows of cell j over halves [48sh,48sh+48) as 96
// f16x2 VGPRs (waves_per_eu(1,1) -> 1 wave/SIMD -> ~512 reg budget).
// Reduce = ONE dpp xor1 add per gate; both pair-lanes redundantly apply all 4
// activations and carry identical c -> no selects, no bcasts, no extra
// cross-lane. Waves at the barrier: 3. h history f16 in a rolling 512-step
// LDS buffer; fc projection bulk-flushed every 512 steps.

constexpr int HH   = 96;
constexpr int BB   = 32;
constexpr int TT   = 16384;
constexpr int TH   = 192;   // 3 waves
constexpr int NS   = 512;   // h history window
constexpr int ROWP = 104;   // halves per row: 208 B (16B-aligned rows)
constexpr int CH   = 2048;  // x chunk in LDS

typedef _Float16 f16x2 __attribute__((ext_vector_type(2)));

__device__ __forceinline__ float dot2_f16(f16x2 a, f16x2 b, float c) {
    float d;
    int ai = __builtin_bit_cast(int, a);
    int bi = __builtin_bit_cast(int, b);
    asm("v_dot2_f32_f16 %0, %1, %2, %3" : "=v"(d) : "v"(ai), "v"(bi), "v"(c));
    return d;
}

template <int CTRL>
__device__ __forceinline__ float dpp_add(float v) {
    int r = __builtin_amdgcn_mov_dpp(__builtin_bit_cast(int, v), CTRL, 0xF, 0xF, true);
    return v + __builtin_bit_cast(float, r);
}
constexpr int DPP_XOR1 = 0xB1;  // quad_perm [1,0,3,2]

__device__ __forceinline__ float sigm(float v) {
    return __builtin_amdgcn_rcpf(1.0f + __expf(-v));
}
__device__ __forceinline__ float tanh_f(float v) {
    return fmaf(2.0f, __builtin_amdgcn_rcpf(1.0f + __expf(-2.0f * v)), -1.0f);
}

__attribute__((amdgpu_flat_work_group_size(TH, TH), amdgpu_waves_per_eu(1, 1)))
__global__ void lstm_kernel(const float* __restrict__ x,
                            const float* __restrict__ w_ih,
                            const float* __restrict__ w_hh,
                            const float* __restrict__ b_ih,
                            const float* __restrict__ b_hh,
                            const float* __restrict__ fc_w,
                            const float* __restrict__ fc_b,
                            float* __restrict__ out) {
    __shared__ __align__(16) _Float16 hist[NS * ROWP];  // ~106 KB rolling h
    __shared__ float xs[CH];                            // 8 KB x chunk
    __shared__ float fcw_s[HH];

    const int tid = threadIdx.x;
    const int b   = blockIdx.x;
    const int j   = tid >> 1;    // cell 0..95
    const int sh  = tid & 1;     // k-half: halves [48sh, 48sh+48)

    // ---- one-time: all 4 gate rows of cell j, 48-half slice -> 96 f16x2 ----
    f16x2 W[4][24];
#pragma unroll
    for (int g = 0; g < 4; ++g) {
        const float* wr = w_hh + (g * HH + j) * HH + 48 * sh;
#pragma unroll
        for (int m = 0; m < 24; ++m)
            W[g][m] = f16x2{(_Float16)wr[2 * m], (_Float16)wr[2 * m + 1]};
    }
#pragma unroll
    for (int g = 0; g < 4; ++g)
#pragma unroll
        for (int m = 0; m < 24; ++m) asm volatile("" : "+v"(W[g][m]));

    float wih[4], bias[4];
#pragma unroll
    for (int g = 0; g < 4; ++g) {
        wih[g]  = w_ih[g * HH + j];
        bias[g] = b_ih[g * HH + j] + b_hh[g * HH + j];
    }
    const float fcb = fc_b[0];
    float c = 0.0f;   // carried identically by both pair-lanes

    for (int i = tid; i < HH; i += TH) {
        fcw_s[i] = fc_w[i];
        hist[(NS - 1) * ROWP + i] = (_Float16)0.0f;  // h(-1) = 0
    }

    // Bulk fc projection for steps [t0, t0+NS): out = hist.fcw + fcb + x
    auto flush = [&](int t0) {
        for (int i = tid; i < NS; i += TH) {
            const uint2* hr = (const uint2*)(hist + i * ROWP);
            float a = 0.0f;
#pragma unroll
            for (int m = 0; m < 24; ++m) {
                uint2 u = hr[m];
                f16x2 p0 = __builtin_bit_cast(f16x2, u.x);
                f16x2 p1 = __builtin_bit_cast(f16x2, u.y);
                a = fmaf((float)p0.x, fcw_s[4 * m + 0], a);
                a = fmaf((float)p0.y, fcw_s[4 * m + 1], a);
                a = fmaf((float)p1.x, fcw_s[4 * m + 2], a);
                a = fmaf((float)p1.y, fcw_s[4 * m + 3], a);
            }
            out[(t0 + i) * BB + b] = a + fcb + xs[(t0 + i) & (CH - 1)];
        }
    };

    for (int t = 0; t < TT; ++t) {
        if (t > 0 && (t & (NS - 1)) == 0) {   // flush BEFORE any xs refill
            flush(t - NS);
            __syncthreads();
        }
        if ((t & (CH - 1)) == 0) {            // covers t=0 (also init barrier)
            for (int i = tid; i < CH; i += TH) xs[i] = x[(t + i) * BB + b];
            __syncthreads();
        }

        // ---- h(t-1) slice: 6 x ds_read_b128 (16B-aligned) ----
        const int pr = (t - 1) & (NS - 1);    // t=0 -> 511 (zeros)
        const uint4* hrow = (const uint4*)(hist + pr * ROWP + 48 * sh);
        uint4 u0 = hrow[0], u1 = hrow[1], u2 = hrow[2];
        uint4 u3 = hrow[3], u4 = hrow[4], u5 = hrow[5];
        f16x2 h2[24] = {
            __builtin_bit_cast(f16x2, u0.x), __builtin_bit_cast(f16x2, u0.y),
            __builtin_bit_cast(f16x2, u0.z), __builtin_bit_cast(f16x2, u0.w),
            __builtin_bit_cast(f16x2, u1.x), __builtin_bit_cast(f16x2, u1.y),
            __builtin_bit_cast(f16x2, u1.z), __builtin_bit_cast(f16x2, u1.w),
            __builtin_bit_cast(f16x2, u2.x), __builtin_bit_cast(f16x2, u2.y),
            __builtin_bit_cast(f16x2, u2.z), __builtin_bit_cast(f16x2, u2.w),
            __builtin_bit_cast(f16x2, u3.x), __builtin_bit_cast(f16x2, u3.y),
            __builtin_bit_cast(f16x2, u3.z), __builtin_bit_cast(f16x2, u3.w),
            __builtin_bit_cast(f16x2, u4.x), __builtin_bit_cast(f16x2, u4.y),
            __builtin_bit_cast(f16x2, u4.z), __builtin_bit_cast(f16x2, u4.w),
            __builtin_bit_cast(f16x2, u5.x), __builtin_bit_cast(f16x2, u5.y),
            __builtin_bit_cast(f16x2, u5.z), __builtin_bit_cast(f16x2, u5.w)};
        const float xv = xs[t & (CH - 1)];

        // ---- 4 gates x 24 dots (2 parallel chains of 12) ----
        float acc[4];
#pragma unroll
        for (int g = 0; g < 4; ++g) {
            float e0 = 0.0f, e1 = 0.0f;
#pragma unroll
            for (int m = 0; m < 12; ++m) e0 = dot2_f16(W[g][m], h2[m], e0);
#pragma unroll
            for (int m = 12; m < 24; ++m) e1 = dot2_f16(W[g][m], h2[m], e1);
            acc[g] = e0 + e1;
        }

        // ---- 1-level pair reduce: both lanes get all 4 full gate sums ----
#pragma unroll
        for (int g = 0; g < 4; ++g) acc[g] = dpp_add<DPP_XOR1>(acc[g]);

        // ---- both lanes: bias + activations + identical c/h update ----
        const float iv = sigm(acc[0] + fmaf(xv, wih[0], bias[0]));
        const float fv = sigm(acc[1] + fmaf(xv, wih[1], bias[1]));
        const float gv = tanh_f(acc[2] + fmaf(xv, wih[2], bias[2]));
        const float ov = sigm(acc[3] + fmaf(xv, wih[3], bias[3]));
        c = fmaf(fv, c, iv * gv);
        const float h = ov * tanh_f(c);
        if (sh == 0) hist[(t & (NS - 1)) * ROWP + j] = (_Float16)h;
        __syncthreads();   // h(t) visible; hist row reuse safe (3 waves only)
    }
    flush(TT - NS);        // last window (loop ended with a barrier)
}

extern "C" void kernel_launch(void* const* d_in, const int* in_sizes, int n_in,
                              void* d_out, int out_size, void* d_ws, size_t ws_size,
                              hipStream_t stream) {
    const float* x    = (const float*)d_in[0];
    const float* w_ih = (const float*)d_in[1];
    const float* w_hh = (const float*)d_in[2];
    const float* b_ih = (const float*)d_in[3];
    const float* b_hh = (const float*)d_in[4];
    const float* fc_w = (const float*)d_in[5];
    const float* fc_b = (const float*)d_in[6];
    float* out = (float*)d_out;

    lstm_kernel<<<dim3(BB), dim3(TH), 0, stream>>>(x, w_ih, w_hh, b_ih, b_hh,
                                                   fc_w, fc_b, out);
}